// Round 1
// baseline (9347.417 us; speedup 1.0000x reference)
//
#include <hip/hip_runtime.h>
#include <hip/hip_bf16.h>

// Bidirectional LSTM, B=256, S=256, E=300, H=512.
// Design: persistent cooperative scan kernel. 256 WGs = 2 dirs x 4 batch-tiles(64) x 32 col-tiles(16 h-cols).
// Per step each WG computes a 64x(4x16) gate tile via bf16 MFMA with K=832 (=512 h + 320 padded emb),
// then does the gate nonlinearity + c/h update for its exclusively-owned piece.
// h is double-buffered by step parity; per-step sync is a group-local (dir,batch-tile) atomic barrier (32 WGs).

#define SQ 256   // sequence length
#define NB 256   // batch
#define HD 512   // hidden
#define ED 300   // embedding
#define EP 320   // padded embedding
#define KK 832   // 512 + 320
#define G4 2048  // 4*H

typedef __attribute__((ext_vector_type(8))) short bf16x8;
typedef __attribute__((ext_vector_type(4))) float f32x4;

__device__ __forceinline__ unsigned short f2bf(float x) {
  union { float f; unsigned u; } v; v.f = x;
  unsigned r = v.u + 0x7FFFu + ((v.u >> 16) & 1u);   // round-to-nearest-even
  return (unsigned short)(r >> 16);
}
__device__ __forceinline__ float sigf(float x) { return 1.f / (1.f + __expf(-x)); }
__device__ __forceinline__ float tanhf_(float x) {
  float t = __expf(-2.f * fabsf(x));
  float r = (1.f - t) / (1.f + t);
  return x < 0.f ? -r : r;
}

// ---- prep: zero state region (hbuf + cws + bar) ----
__global__ void k_zero(unsigned* __restrict__ p, int n) {
  int i = blockIdx.x * 256 + threadIdx.x;
  if (i < n) p[i] = 0u;
}

// ---- prep: W' bf16 [2][2048][832] = [W_hh | W_ih | 0-pad] per row ----
__global__ void k_prep_w(const float* __restrict__ Wihf, const float* __restrict__ Whhf,
                         const float* __restrict__ Wihb, const float* __restrict__ Whhb,
                         unsigned short* __restrict__ Wp) {
  int idx = blockIdx.x * 256 + threadIdx.x;
  if (idx >= 2 * G4 * KK) return;
  int d = idx / (G4 * KK);
  int rem = idx % (G4 * KK);
  int R = rem / KK, k = rem % KK;
  const float* Whh = d ? Whhb : Whhf;
  const float* Wih = d ? Wihb : Wihf;
  float v = 0.f;
  if (k < HD) v = Whh[R * HD + k];
  else if (k < HD + ED) v = Wih[R * ED + (k - HD)];
  Wp[idx] = f2bf(v);
}

// ---- prep: xe bf16 [S][B][320] = emb[tok] padded ----
__global__ void k_prep_xe(const int* __restrict__ x, const float* __restrict__ emb,
                          unsigned short* __restrict__ xe) {
  const int bidx = blockIdx.x;           // t*NB + b
  const int t = bidx / NB, b = bidx % NB;
  const int tok = x[b * SQ + t];         // x is (B,1,S)
  unsigned short* dst = xe + (size_t)(t * NB + b) * EP;
  const float* src = emb + (size_t)tok * ED;
  for (int e = threadIdx.x; e < EP; e += 64)
    dst[e] = (e < ED) ? f2bf(src[e]) : (unsigned short)0;
}

// ---- main persistent scan ----
__global__ __launch_bounds__(256, 1) void lstm_scan(
    const unsigned short* __restrict__ Wp,    // [2][2048][832] bf16
    const unsigned short* __restrict__ xe,    // [S][B][320] bf16
    const float* __restrict__ bias_f,
    const float* __restrict__ bias_b,
    unsigned short* __restrict__ hbuf,        // [2 parity][2 dir][B][H] bf16
    float* __restrict__ cws,                  // [2][B][H] f32
    float* __restrict__ hfin,                 // [2][B][H] f32
    unsigned* __restrict__ bar)               // [8]
{
  const int p = blockIdx.x;
  const int g8 = p & 7;        // -> XCD slot; also the barrier group id
  const int d  = g8 >> 2;      // direction
  const int bg = g8 & 3;       // batch tile (64 rows)
  const int ct = p >> 3;       // col tile (16 h-cols)
  const int tid = threadIdx.x;
  const int lane = tid & 63;
  const int wv = tid >> 6;     // wave 0..3 -> batch sub-block of 16
  const int q = lane >> 4;     // 0..3
  const int lm = lane & 15;

  __shared__ unsigned short lsA[64 * 72];   // stride 72 (=144B, 16B-aligned, bank-spread)
  __shared__ unsigned short lsB[64 * 72];

  const float* bias = d ? bias_b : bias_f;
  const int ncol = (ct << 4) | lm;          // h column 0..511 (per-lane constant)
  const float Bi = bias[ncol];
  const float Bf = bias[512 + ncol];
  const float Bg = bias[1024 + ncol];
  const float Bo = bias[1536 + ncol];

  const int srow = tid >> 3;                // staging row 0..31
  const int scol = (tid & 7) << 3;          // staging k-offset (x8 bf16 = 16B)
  const unsigned gid = (unsigned)g8;

  for (int t = 0; t < SQ; ++t) {
    const int tx = d ? (SQ - 1 - t) : t;
    const int rp = t & 1;
    const unsigned short* hin = hbuf + ((size_t)((rp * 2 + d) * NB + bg * 64)) * HD;
    f32x4 acc0 = {0.f, 0.f, 0.f, 0.f}, acc1 = acc0, acc2 = acc0, acc3 = acc0;

    for (int ch = 0; ch < 13; ++ch) {
      const int k0 = ch << 6;
      #pragma unroll
      for (int it = 0; it < 2; ++it) {
        const int row = it * 32 + srow;
        bf16x8 va;
        if (ch < 8) {
          va = *(const bf16x8*)(hin + row * HD + k0 + scol);
        } else {
          va = *(const bf16x8*)(xe + ((size_t)tx * NB + bg * 64 + row) * EP + (k0 - 512) + scol);
        }
        *(bf16x8*)&lsA[row * 72 + scol] = va;
        // W' rows for this col-tile: gate g = row>>4, j = row&15 -> R = g*512 + ct*16 + j
        const int R = ((row >> 4) << 9) + (ct << 4) + (row & 15);
        bf16x8 vb = *(const bf16x8*)(Wp + ((size_t)d * G4 + R) * KK + k0 + scol);
        *(bf16x8*)&lsB[row * 72 + scol] = vb;
      }
      __syncthreads();
      #pragma unroll
      for (int kk = 0; kk < 2; ++kk) {
        const int ko = (q << 3) + (kk << 5);
        bf16x8 a  = *(const bf16x8*)&lsA[(wv * 16 + lm) * 72 + ko];
        bf16x8 b0 = *(const bf16x8*)&lsB[( 0 + lm) * 72 + ko];
        bf16x8 b1 = *(const bf16x8*)&lsB[(16 + lm) * 72 + ko];
        bf16x8 b2 = *(const bf16x8*)&lsB[(32 + lm) * 72 + ko];
        bf16x8 b3 = *(const bf16x8*)&lsB[(48 + lm) * 72 + ko];
        acc0 = __builtin_amdgcn_mfma_f32_16x16x32_bf16(a, b0, acc0, 0, 0, 0);
        acc1 = __builtin_amdgcn_mfma_f32_16x16x32_bf16(a, b1, acc1, 0, 0, 0);
        acc2 = __builtin_amdgcn_mfma_f32_16x16x32_bf16(a, b2, acc2, 0, 0, 0);
        acc3 = __builtin_amdgcn_mfma_f32_16x16x32_bf16(a, b3, acc3, 0, 0, 0);
      }
      __syncthreads();
    }

    // gate update: lane l, reg r owns (brow = bg*64 + wv*16 + q*4 + r, ncol)
    unsigned short* hout = hbuf + ((size_t)(((rp ^ 1) * 2 + d) * NB)) * HD;
    #pragma unroll
    for (int r = 0; r < 4; ++r) {
      const int brow = bg * 64 + wv * 16 + q * 4 + r;
      const float gi = acc0[r] + Bi;
      const float gf = acc1[r] + Bf;
      const float gg = acc2[r] + Bg;
      const float go = acc3[r] + Bo;
      const int cidx = (d * NB + brow) * HD + ncol;
      float c = sigf(gf) * cws[cidx] + sigf(gi) * tanhf_(gg);
      float h = sigf(go) * tanhf_(c);
      cws[cidx] = c;
      hout[brow * HD + ncol] = f2bf(h);
      if (t == SQ - 1) hfin[cidx] = h;
    }

    // group barrier: 32 WGs sharing (d, bg). Monotonic counter, device scope.
    __threadfence();
    __syncthreads();
    if (tid == 0) {
      __hip_atomic_fetch_add(&bar[gid], 1u, __ATOMIC_RELEASE, __HIP_MEMORY_SCOPE_AGENT);
      const unsigned target = 32u * (unsigned)(t + 1);
      while (__hip_atomic_load(&bar[gid], __ATOMIC_ACQUIRE, __HIP_MEMORY_SCOPE_AGENT) < target) {
        __builtin_amdgcn_s_sleep(2);
      }
      __threadfence();
    }
    __syncthreads();
  }
}

// ---- final projection: out[b] = sum_k hidden[b][k]*W_out[k] + b_out ----
__global__ void k_out(const float* __restrict__ hfin, const float* __restrict__ Wo,
                      const float* __restrict__ bo, float* __restrict__ out) {
  const int b = blockIdx.x;
  const int tid = threadIdx.x;
  float s = 0.f;
  for (int k = tid; k < 1024; k += 256)
    s += hfin[((k >> 9) * NB + b) * HD + (k & 511)] * Wo[k];
  #pragma unroll
  for (int o = 32; o > 0; o >>= 1) s += __shfl_down(s, o, 64);
  __shared__ float red[4];
  if ((tid & 63) == 0) red[tid >> 6] = s;
  __syncthreads();
  if (tid == 0) out[b] = red[0] + red[1] + red[2] + red[3] + bo[0];
}

extern "C" void kernel_launch(void* const* d_in, const int* in_sizes, int n_in,
                              void* d_out, int out_size, void* d_ws, size_t ws_size,
                              hipStream_t stream) {
  const int*   x    = (const int*)d_in[0];
  const float* emb  = (const float*)d_in[1];
  const float* Wihf = (const float*)d_in[2];
  const float* Whhf = (const float*)d_in[3];
  const float* bf   = (const float*)d_in[4];
  const float* Wihb = (const float*)d_in[5];
  const float* Whhb = (const float*)d_in[6];
  const float* bb   = (const float*)d_in[7];
  const float* Wo   = (const float*)d_in[8];
  const float* bo   = (const float*)d_in[9];
  float* out = (float*)d_out;

  // ws layout (all 16B aligned):
  //   Wp   @ 0          : 2*2048*832*2  = 6,815,744
  //   xe   @ 6,815,744  : 256*256*320*2 = 41,943,040
  //   hbuf @ 48,758,784 : 2*2*256*512*2 = 1,048,576
  //   cws  @ 49,807,360 : 2*256*512*4   = 1,048,576
  //   bar  @ 50,855,936 : 256
  //   hfin @ 50,856,192 : 2*256*512*4   = 1,048,576
  char* ws = (char*)d_ws;
  unsigned short* Wp   = (unsigned short*)(ws + 0);
  unsigned short* xe   = (unsigned short*)(ws + 6815744);
  unsigned short* hbuf = (unsigned short*)(ws + 48758784);
  float*          cws  = (float*)(ws + 49807360);
  unsigned*       bar  = (unsigned*)(ws + 50855936);
  float*          hfin = (float*)(ws + 50856192);

  // zero hbuf + cws + bar (contiguous 2,097,408 B = 524,352 words)
  k_zero<<<2049, 256, 0, stream>>>((unsigned*)(ws + 48758784), 524352);
  k_prep_w<<<(2 * G4 * KK + 255) / 256, 256, 0, stream>>>(Wihf, Whhf, Wihb, Whhb, Wp);
  k_prep_xe<<<SQ * NB, 64, 0, stream>>>(x, emb, xe);

  void* args[] = { (void*)&Wp, (void*)&xe, (void*)&bf, (void*)&bb,
                   (void*)&hbuf, (void*)&cws, (void*)&hfin, (void*)&bar };
  hipLaunchCooperativeKernel((const void*)lstm_scan, dim3(256), dim3(256), args, 0, stream);

  k_out<<<NB, 256, 0, stream>>>(hfin, Wo, bo, out);
}